// Round 4
// baseline (293.623 us; speedup 1.0000x reference)
//
#include <hip/hip_runtime.h>
#include <hip/hip_bf16.h>

// Cost-volume: out[b,c,d,h,w] = |ref[b,c,h,w] - tgt[b,c,h,w-d]| * (w>=d)
// Inputs: FP32. Output: FP32 (reference output dtype; round-3 bf16-store
// experiment produced full-scale error -> checker reads fp32).
// Four volumes fused in one launch; each thread computes 4 consecutive w and
// stores one float4 (16B). All volume element counts are multiples of 1024
// (256 thr * 4 elem) -> no tail handling.

template<int H, int W, int D>
__device__ __forceinline__ void fv_block(const float* __restrict__ ref,
                                         const float* __restrict__ tgt,
                                         float* __restrict__ out,
                                         int i /* index of 4-elem group */)
{
    constexpr int W4 = W / 4;
    int w4 = i % W4;
    int t  = i / W4;
    int h  = t % H;
    t /= H;
    int d  = t % D;
    int bc = t / D;   // b*C + c

    const int row = (bc * H + h) * W;
    const float* refrow = ref + row;
    const float* tgtrow = tgt + row;
    const int w0 = w4 * 4;

    // ref: 16B-aligned vector load (row and w0 are multiples of 4 elems)
    float4 rv = *(const float4*)(refrow + w0);
    float r[4] = {rv.x, rv.y, rv.z, rv.w};

    float4 o;
    float* op = (float*)&o;
    #pragma unroll
    for (int j = 0; j < 4; ++j) {
        int w = w0 + j;
        float v = 0.0f;
        if (w >= d) {
            v = fabsf(r[j] - tgtrow[w - d]);   // tgt: scalar load, L2-resident
        }
        op[j] = v;
    }
    ((float4*)out)[i] = o;  // 16B coalesced fp32 store
}

// Block ranges (largest volume first for scheduling):
//  feat3: H=96 W=160 D=48  groups=11796480 -> 46080 blocks, out off 6727680
//  feat4: H=48 W=80  D=24  groups=1474560  ->  5760 blocks, out off  829440
//  feat5: H=24 W=40  D=12  groups=184320   ->   720 blocks, out off   92160
//  feat6: H=12 W=20  D=6   groups=23040    ->    90 blocks, out off       0
#define NB3 46080
#define NB4 5760
#define NB5 720
#define NB6 90

__global__ __launch_bounds__(256) void fv_fused(
    const float* __restrict__ c40, const float* __restrict__ c41,
    const float* __restrict__ c30, const float* __restrict__ c31,
    const float* __restrict__ c20, const float* __restrict__ c21,
    const float* __restrict__ c10, const float* __restrict__ c11,
    float* __restrict__ out)
{
    const int b = blockIdx.x;
    const int tid = threadIdx.x;
    if (b < NB3) {
        fv_block<96, 160, 48>(c10, c11, out + 6727680, b * 256 + tid);
    } else if (b < NB3 + NB4) {
        fv_block<48, 80, 24>(c20, c21, out + 829440, (b - NB3) * 256 + tid);
    } else if (b < NB3 + NB4 + NB5) {
        fv_block<24, 40, 12>(c30, c31, out + 92160, (b - NB3 - NB4) * 256 + tid);
    } else {
        fv_block<12, 20, 6>(c40, c41, out + 0, (b - NB3 - NB4 - NB5) * 256 + tid);
    }
}

extern "C" void kernel_launch(void* const* d_in, const int* in_sizes, int n_in,
                              void* d_out, int out_size, void* d_ws, size_t ws_size,
                              hipStream_t stream)
{
    const float* c40 = (const float*)d_in[0];
    const float* c41 = (const float*)d_in[1];
    const float* c30 = (const float*)d_in[2];
    const float* c31 = (const float*)d_in[3];
    const float* c20 = (const float*)d_in[4];
    const float* c21 = (const float*)d_in[5];
    const float* c10 = (const float*)d_in[6];
    const float* c11 = (const float*)d_in[7];
    float* out = (float*)d_out;

    const int nblocks = NB3 + NB4 + NB5 + NB6;  // 52650
    fv_fused<<<nblocks, 256, 0, stream>>>(c40, c41, c30, c31, c20, c21,
                                          c10, c11, out);
}

// Round 6
// 285.907 us; speedup vs baseline: 1.0270x; 1.0270x over previous
//
#include <hip/hip_runtime.h>
#include <hip/hip_bf16.h>

// Cost-volume: out[b,c,d,h,w] = |ref[b,c,h,w] - tgt[b,c,h,w-d]| * (w>=d)
// Inputs: FP32. Output: FP32. R4 PASSED (absmax 0.0, dur 293.6us; ~260us of
// that is harness poison fills at 6.7 TB/s). This round: nontemporal float4
// stores via ext_vector_type (HIP float4 is a class -> builtin rejects it).

typedef float v4f __attribute__((ext_vector_type(4)));

template<int H, int W, int D>
__device__ __forceinline__ void fv_block(const float* __restrict__ ref,
                                         const float* __restrict__ tgt,
                                         float* __restrict__ out,
                                         int i /* index of 4-elem group */)
{
    constexpr int W4 = W / 4;
    int w4 = i % W4;
    int t  = i / W4;
    int h  = t % H;
    t /= H;
    int d  = t % D;
    int bc = t / D;   // b*C + c

    const int row = (bc * H + h) * W;
    const float* refrow = ref + row;
    const float* tgtrow = tgt + row;
    const int w0 = w4 * 4;

    // ref: 16B-aligned vector load (row and w0 are multiples of 4 elems)
    v4f rv = *(const v4f*)(refrow + w0);

    v4f o;
    #pragma unroll
    for (int j = 0; j < 4; ++j) {
        int w = w0 + j;
        float v = 0.0f;
        if (w >= d) {
            v = fabsf(rv[j] - tgtrow[w - d]);   // tgt: scalar load, cache-resident
        }
        o[j] = v;
    }
    // 16B coalesced streaming store (nt): output is never re-read.
    __builtin_nontemporal_store(o, (v4f*)out + i);
}

// Block ranges (largest volume first for scheduling):
//  feat3: H=96 W=160 D=48  groups=11796480 -> 46080 blocks, out off 6727680
//  feat4: H=48 W=80  D=24  groups=1474560  ->  5760 blocks, out off  829440
//  feat5: H=24 W=40  D=12  groups=184320   ->   720 blocks, out off   92160
//  feat6: H=12 W=20  D=6   groups=23040    ->    90 blocks, out off       0
#define NB3 46080
#define NB4 5760
#define NB5 720
#define NB6 90

__global__ __launch_bounds__(256) void fv_fused(
    const float* __restrict__ c40, const float* __restrict__ c41,
    const float* __restrict__ c30, const float* __restrict__ c31,
    const float* __restrict__ c20, const float* __restrict__ c21,
    const float* __restrict__ c10, const float* __restrict__ c11,
    float* __restrict__ out)
{
    const int b = blockIdx.x;
    const int tid = threadIdx.x;
    if (b < NB3) {
        fv_block<96, 160, 48>(c10, c11, out + 6727680, b * 256 + tid);
    } else if (b < NB3 + NB4) {
        fv_block<48, 80, 24>(c20, c21, out + 829440, (b - NB3) * 256 + tid);
    } else if (b < NB3 + NB4 + NB5) {
        fv_block<24, 40, 12>(c30, c31, out + 92160, (b - NB3 - NB4) * 256 + tid);
    } else {
        fv_block<12, 20, 6>(c40, c41, out + 0, (b - NB3 - NB4 - NB5) * 256 + tid);
    }
}

extern "C" void kernel_launch(void* const* d_in, const int* in_sizes, int n_in,
                              void* d_out, int out_size, void* d_ws, size_t ws_size,
                              hipStream_t stream)
{
    const float* c40 = (const float*)d_in[0];
    const float* c41 = (const float*)d_in[1];
    const float* c30 = (const float*)d_in[2];
    const float* c31 = (const float*)d_in[3];
    const float* c20 = (const float*)d_in[4];
    const float* c21 = (const float*)d_in[5];
    const float* c10 = (const float*)d_in[6];
    const float* c11 = (const float*)d_in[7];
    float* out = (float*)d_out;

    const int nblocks = NB3 + NB4 + NB5 + NB6;  // 52650
    fv_fused<<<nblocks, 256, 0, stream>>>(c40, c41, c30, c31, c20, c21,
                                          c10, c11, out);
}